// Round 4
// baseline (384.445 us; speedup 1.0000x reference)
//
#include <hip/hip_runtime.h>
#include <hip/hip_bf16.h>

#define O_N 128
#define D_N 128
#define F_LS 64
#define T_MAX 128
#define FE_N 16
#define H_GRU 64
#define NH 128
#define NO 64
#define PH 128

typedef _Float16 f16;
typedef __fp16 hf2 __attribute__((ext_vector_type(2)));
typedef f16 f16x4 __attribute__((ext_vector_type(4)));
typedef f16 f16x8 __attribute__((ext_vector_type(8)));
typedef float f32x4 __attribute__((ext_vector_type(4)));

__device__ __forceinline__ float fast_sigmoid(float x) {
    return __builtin_amdgcn_rcpf(1.f + __expf(-x));
}

// -------- encoders + PA / transposed-PB (bp1 folded) ; also zeroes d_out ----
__global__ __launch_bounds__(128) void k_enc(
    const float* __restrict__ O_feats, const float* __restrict__ D_feats,
    const float* __restrict__ WO1, const float* __restrict__ bO1,
    const float* __restrict__ WO2, const float* __restrict__ bO2,
    const float* __restrict__ WO3, const float* __restrict__ bO3,
    const float* __restrict__ WD1, const float* __restrict__ bD1,
    const float* __restrict__ WD2, const float* __restrict__ bD2,
    const float* __restrict__ WD3, const float* __restrict__ bD3,
    const float* __restrict__ Wp1, const float* __restrict__ bp1,
    float* __restrict__ PA, float* __restrict__ PBt, float* __restrict__ d_out)
{
    __shared__ float h1[NH];
    __shared__ float h2[NH];
    __shared__ float ev[NO];
    const int b = blockIdx.x;
    const int enc = b >> 7;
    const int row = b & 127;
    const int t = threadIdx.x;
    if (b == 0 && t == 0) d_out[0] = 0.f;

    const float* x  = (enc ? D_feats : O_feats) + row * F_LS;
    const float* W1 = enc ? WD1 : WO1;  const float* b1 = enc ? bD1 : bO1;
    const float* W2 = enc ? WD2 : WO2;  const float* b2 = enc ? bD2 : bO2;
    const float* W3 = enc ? WD3 : WO3;  const float* b3 = enc ? bD3 : bO3;

    float a = b1[t];
    #pragma unroll 8
    for (int k = 0; k < F_LS; ++k) a += x[k] * W1[k * NH + t];
    h1[t] = fmaxf(a, 0.f);
    __syncthreads();

    a = b2[t];
    #pragma unroll 8
    for (int k = 0; k < NH; ++k) a += h1[k] * W2[k * NH + t];
    h2[t] = fmaxf(a, 0.f);
    __syncthreads();

    if (t < NO) {
        a = b3[t];
        #pragma unroll 8
        for (int k = 0; k < NH; ++k) a += h2[k] * W3[k * NO + t];
        ev[t] = a;
    }
    __syncthreads();

    const float* Wp = Wp1 + (enc ? NO * PH : 0);
    a = 0.f;
    #pragma unroll 8
    for (int k = 0; k < NO; ++k) a += ev[k] * Wp[k * PH + t];
    if (enc) PBt[t * 128 + row] = a + bp1[t];   // transposed + bias folded
    else     PA[row * PH + t] = a;
}

// ---------------- pair scores (coalesced PBt stream) ----------------
__global__ __launch_bounds__(128) void k_pair(
    const float* __restrict__ PA, const float* __restrict__ PBt,
    const float* __restrict__ Wp2, const float* __restrict__ bp2,
    float* __restrict__ s_pair)
{
    const int i = blockIdx.x;
    const int j = threadIdx.x;
    __shared__ float pa[PH];
    __shared__ float w2s[PH];
    pa[j]  = PA[i * PH + j];
    w2s[j] = Wp2[j];
    __syncthreads();
    float acc = 0.f;
    #pragma unroll 8
    for (int c = 0; c < PH; ++c)
        acc += w2s[c] * fmaxf(pa[c] + PBt[c * 128 + j], 0.f);
    float z = acc + bp2[0];
    float sp = fmaxf(z, 0.f) + log1pf(__expf(-fabsf(z)));
    s_pair[i * 128 + j] = sp;
}

// ------- counting sort by length, DESCENDING, one block, LDS atomics -------
__global__ __launch_bounds__(1024) void k_sort(
    const int* __restrict__ lengths, int* __restrict__ perm)
{
    __shared__ int cnt[130];
    __shared__ int suf[130];
    const int t = threadIdx.x;
    if (t < 130) cnt[t] = 0;
    __syncthreads();
    for (int i = t; i < 16384; i += 1024) atomicAdd(&cnt[lengths[i]], 1);
    __syncthreads();
    if (t < 130) suf[t] = cnt[t];
    __syncthreads();
    for (int d = 1; d < 130; d <<= 1) {
        int v = 0;
        if (t < 130) { v = suf[t]; if (t + d < 130) v += suf[t + d]; }
        __syncthreads();
        if (t < 130) suf[t] = v;
        __syncthreads();
    }
    if (t < 129) cnt[t] = (t + 1 < 130) ? suf[t + 1] : 0;
    __syncthreads();
    for (int i = t; i < 16384; i += 1024) {
        int pos = atomicAdd(&cnt[lengths[i]], 1);
        perm[pos] = i;
    }
}

// ---- GRU: independent 4-wave blocks (decoupled barriers, round-0 style) ----
// grid 1024 x 256, all blocks resident (4/CU). Group remap for equal-length
// co-residency: dispatch puts blocks {m, m+256, m+512, m+768} on one CU;
// g = (b%256)*4 + b/256 makes those groups {4m..4m+3} (adjacent sorted ranks,
// near-equal maxlen) -> no 4->1 per-CU concurrency decay at the tail.
// Wave w owns hidden cols [16w,16w+16); lane(q=l>>4,n=l&15): pair n,
// cols 16w+4q+0..3. One barrier per step; x-first MFMA ordering.
__global__ __launch_bounds__(256, 4) void k_gru(
    const float* __restrict__ seqs, const int* __restrict__ lengths,
    const int* __restrict__ perm,
    const float* __restrict__ W_ih, const float* __restrict__ b_ih,
    const float* __restrict__ W_hh, const float* __restrict__ b_hh,
    const float* __restrict__ Ws, const float* __restrict__ bs,
    const float* __restrict__ s_pair, float* __restrict__ d_out)
{
    __shared__ __align__(16) f16 hbuf[2][16 * 72];   // [buf][pair][64 + 8 pad]
    __shared__ float red[64];
    const int tid = threadIdx.x;
    const int w  = tid >> 6;
    const int l  = tid & 63;
    const int q  = l >> 4;
    const int n  = l & 15;
    const int c  = w * 16 + n;          // W-frag column (m-row of A-tile)
    const int colbase = w * 16 + q * 4; // this lane's 4 hidden cols
    const int g  = (blockIdx.x & 255) * 4 + (blockIdx.x >> 8);  // remap
    const int pb = g * 16;
    const float S_RZ = -1.4426950408889634f;   // -log2(e)
    const float S_N  =  2.8853900817779268f;   // 2*log2(e)

    // W fragments (A-operand via m=lane&15):
    f16x8 wh[3][2], wi[3];
    #pragma unroll
    for (int gg = 0; gg < 3; ++gg) {
        const int gb = gg * 64;
        const float s = (gg < 2) ? S_RZ : S_N;
        #pragma unroll
        for (int ks = 0; ks < 2; ++ks)
            #pragma unroll
            for (int j = 0; j < 8; ++j)
                wh[gg][ks][j] = (f16)(W_hh[(ks * 32 + q * 8 + j) * 192 + gb + c] * s);
        #pragma unroll
        for (int j = 0; j < 8; ++j) {
            int k = q * 8 + j;
            wi[gg][j] = (k < FE_N) ? (f16)(W_ih[k * 192 + gb + c] * s) : (f16)0.f;
        }
    }
    // per-reg bias C-vectors and Ws for this lane's 4 cols
    f32x4 c_r, c_z, c_hn, c_xn;
    float wsc[4];
    #pragma unroll
    for (int r = 0; r < 4; ++r) {
        int col = colbase + r;
        c_r[r]  = S_RZ * (b_ih[col] + b_hh[col]);
        c_z[r]  = S_RZ * (b_ih[64 + col] + b_hh[64 + col]);
        c_hn[r] = S_N * b_hh[128 + col];
        c_xn[r] = S_N * b_ih[128 + col];
        wsc[r]  = Ws[col];
    }
    const int myp   = perm[pb + n];      // this lane's pair
    const int mylen = lengths[myp];
    int ml = mylen;
    ml = max(ml, __shfl_xor(ml, 1));
    ml = max(ml, __shfl_xor(ml, 2));
    ml = max(ml, __shfl_xor(ml, 4));
    ml = max(ml, __shfl_xor(ml, 8));
    const int maxlen = __builtin_amdgcn_readfirstlane(ml);

    // zero h buffer 0 (2304 B = 144 x 16 B)
    {
        f16x8 z8 = {};
        if (tid < 144) *(f16x8*)&hbuf[0][tid * 8] = z8;
    }

    // x: lanes q<2 stream pair n's feats [8q,8q+8); per-substep prefetch bufs
    const float4* xp = (const float4*)(seqs + (size_t)myp * (T_MAX * FE_N)) + q * 2;
    float4 x0a = {0.f, 0.f, 0.f, 0.f}, x0b = x0a, x1a = x0a, x1b = x0a;
    if (q < 2) {
        x0a = xp[0]; x0b = xp[1];        // row t=0
        x1a = xp[4]; x1b = xp[5];        // row t=1 (rows always allocated)
    }
    f16x8 ax = {};                        // q>=2 lanes contribute zeros (K pad)
    float hold[4] = {0.f, 0.f, 0.f, 0.f};
    __syncthreads();

    auto step = [&](int TT, int sub, float4& XA, float4& XB) {
        const f16* hb  = hbuf[sub];
        f16*       hbw = hbuf[sub ^ 1];
        // issue LDS reads first (latency), x-side work fills the gap
        f16x8 bh0 = *(const f16x8*)&hb[n * 72 + 8 * q];
        f16x8 bh1 = *(const f16x8*)&hb[n * 72 + 32 + 8 * q];
        if (q < 2) {
            union { f16x8 v8; hf2 v2[4]; } u;
            u.v2[0] = __builtin_amdgcn_cvt_pkrtz(XA.x, XA.y);
            u.v2[1] = __builtin_amdgcn_cvt_pkrtz(XA.z, XA.w);
            u.v2[2] = __builtin_amdgcn_cvt_pkrtz(XB.x, XB.y);
            u.v2[3] = __builtin_amdgcn_cvt_pkrtz(XB.z, XB.w);
            ax = u.v8;
            int tn = (TT + 2 < maxlen) ? (TT + 2) : (maxlen - 1);
            XA = xp[tn * 4]; XB = xp[tn * 4 + 1];
        }
        // x-first MFMA chains (no LDS dep on first op of r/z/xn)
        f32x4 ar = __builtin_amdgcn_mfma_f32_16x16x32_f16(wi[0], ax, c_r, 0, 0, 0);
        f32x4 az = __builtin_amdgcn_mfma_f32_16x16x32_f16(wi[1], ax, c_z, 0, 0, 0);
        f32x4 xn = __builtin_amdgcn_mfma_f32_16x16x32_f16(wi[2], ax, c_xn, 0, 0, 0);
        ar = __builtin_amdgcn_mfma_f32_16x16x32_f16(wh[0][0], bh0, ar, 0, 0, 0);
        ar = __builtin_amdgcn_mfma_f32_16x16x32_f16(wh[0][1], bh1, ar, 0, 0, 0);
        az = __builtin_amdgcn_mfma_f32_16x16x32_f16(wh[1][0], bh0, az, 0, 0, 0);
        az = __builtin_amdgcn_mfma_f32_16x16x32_f16(wh[1][1], bh1, az, 0, 0, 0);
        f32x4 hn = __builtin_amdgcn_mfma_f32_16x16x32_f16(wh[2][0], bh0, c_hn, 0, 0, 0);
        hn = __builtin_amdgcn_mfma_f32_16x16x32_f16(wh[2][1], bh1, hn, 0, 0, 0);

        const bool live = (TT < mylen);
        #pragma unroll
        for (int r = 0; r < 4; ++r) {
            float rg    = __builtin_amdgcn_rcpf(1.f + __builtin_amdgcn_exp2f(ar[r]));
            float zg    = __builtin_amdgcn_rcpf(1.f + __builtin_amdgcn_exp2f(az[r]));
            float inner = fmaf(rg, hn[r], xn[r]);
            float nn    = fmaf(-2.f, __builtin_amdgcn_rcpf(1.f + __builtin_amdgcn_exp2f(inner)), 1.f);
            float hnew  = fmaf(zg, hold[r] - nn, nn);
            hold[r] = live ? hnew : hold[r];
        }
        union { f16x4 v4; hf2 v2[2]; } hu;
        hu.v2[0] = __builtin_amdgcn_cvt_pkrtz(hold[0], hold[1]);
        hu.v2[1] = __builtin_amdgcn_cvt_pkrtz(hold[2], hold[3]);
        *(f16x4*)&hbw[n * 72 + colbase] = hu.v4;
    };

    #pragma unroll 1
    for (int t = 0; t < maxlen; t += 2) {
        step(t, 0, x0a, x0b);
        __syncthreads();
        if (t + 1 >= maxlen) break;               // block-uniform
        step(t + 1, 1, x1a, x1b);
        __syncthreads();
    }

    // epilogue: p_seq = sigmoid(h @ Ws + bs); contrib = s_pair * p_seq
    float part = hold[0] * wsc[0] + hold[1] * wsc[1] +
                 hold[2] * wsc[2] + hold[3] * wsc[3];
    part += __shfl_xor(part, 16);
    part += __shfl_xor(part, 32);          // sum over q: wave-w partial for pair n
    if (l < 16) red[w * 16 + n] = part;
    __syncthreads();
    if (tid < 16) {
        float s = red[tid] + red[16 + tid] + red[32 + tid] + red[48 + tid];
        float pv = fast_sigmoid(s + bs[0]);
        float contrib = s_pair[perm[pb + tid]] * pv;
        #pragma unroll
        for (int off = 1; off < 16; off <<= 1)
            contrib += __shfl_xor(contrib, off);
        if (tid == 0) atomicAdd(d_out, contrib);
    }
}

extern "C" void kernel_launch(void* const* d_in, const int* in_sizes, int n_in,
                              void* d_out, int out_size, void* d_ws, size_t ws_size,
                              hipStream_t stream)
{
    const float* O_feats = (const float*)d_in[0];
    const float* D_feats = (const float*)d_in[1];
    const float* seqs    = (const float*)d_in[2];
    const int*   lengths = (const int*)d_in[3];
    const float* WO1 = (const float*)d_in[4];  const float* bO1 = (const float*)d_in[5];
    const float* WO2 = (const float*)d_in[6];  const float* bO2 = (const float*)d_in[7];
    const float* WO3 = (const float*)d_in[8];  const float* bO3 = (const float*)d_in[9];
    const float* WD1 = (const float*)d_in[10]; const float* bD1 = (const float*)d_in[11];
    const float* WD2 = (const float*)d_in[12]; const float* bD2 = (const float*)d_in[13];
    const float* WD3 = (const float*)d_in[14]; const float* bD3 = (const float*)d_in[15];
    const float* Wp1 = (const float*)d_in[16]; const float* bp1 = (const float*)d_in[17];
    const float* Wp2 = (const float*)d_in[18]; const float* bp2 = (const float*)d_in[19];
    const float* W_ih = (const float*)d_in[20]; const float* b_ih = (const float*)d_in[21];
    const float* W_hh = (const float*)d_in[22]; const float* b_hh = (const float*)d_in[23];
    const float* Ws   = (const float*)d_in[24]; const float* bs   = (const float*)d_in[25];

    float* out    = (float*)d_out;
    float* PA     = (float*)d_ws;              // 16384 f
    float* PBt    = PA + 128 * 128;            // 16384 f (transposed, bp1 folded)
    float* s_pair = PBt + 128 * 128;           // 16384 f
    int*   perm   = (int*)(s_pair + 16384);    // 16384 i

    k_enc<<<256, 128, 0, stream>>>(O_feats, D_feats,
                                   WO1, bO1, WO2, bO2, WO3, bO3,
                                   WD1, bD1, WD2, bD2, WD3, bD3,
                                   Wp1, bp1, PA, PBt, out);
    k_pair<<<128, 128, 0, stream>>>(PA, PBt, Wp2, bp2, s_pair);
    k_sort<<<1, 1024, 0, stream>>>(lengths, perm);
    k_gru<<<1024, 256, 0, stream>>>(seqs, lengths, perm, W_ih, b_ih, W_hh, b_hh,
                                    Ws, bs, s_pair, out);
}

// Round 5
// 328.727 us; speedup vs baseline: 1.1695x; 1.1695x over previous
//
#include <hip/hip_runtime.h>
#include <hip/hip_bf16.h>

#define O_N 128
#define D_N 128
#define F_LS 64
#define T_MAX 128
#define FE_N 16
#define H_GRU 64
#define NH 128
#define NO 64
#define PH 128

typedef _Float16 f16;
typedef __fp16 hf2 __attribute__((ext_vector_type(2)));
typedef f16 f16x4 __attribute__((ext_vector_type(4)));
typedef f16 f16x8 __attribute__((ext_vector_type(8)));
typedef float f32x4 __attribute__((ext_vector_type(4)));

__device__ __forceinline__ float fast_sigmoid(float x) {
    return __builtin_amdgcn_rcpf(1.f + __expf(-x));
}

// -------- encoders + PA / transposed-PB (bp1 folded) ; also zeroes d_out ----
__global__ __launch_bounds__(128) void k_enc(
    const float* __restrict__ O_feats, const float* __restrict__ D_feats,
    const float* __restrict__ WO1, const float* __restrict__ bO1,
    const float* __restrict__ WO2, const float* __restrict__ bO2,
    const float* __restrict__ WO3, const float* __restrict__ bO3,
    const float* __restrict__ WD1, const float* __restrict__ bD1,
    const float* __restrict__ WD2, const float* __restrict__ bD2,
    const float* __restrict__ WD3, const float* __restrict__ bD3,
    const float* __restrict__ Wp1, const float* __restrict__ bp1,
    float* __restrict__ PA, float* __restrict__ PBt, float* __restrict__ d_out)
{
    __shared__ float h1[NH];
    __shared__ float h2[NH];
    __shared__ float ev[NO];
    const int b = blockIdx.x;
    const int enc = b >> 7;
    const int row = b & 127;
    const int t = threadIdx.x;
    if (b == 0 && t == 0) d_out[0] = 0.f;

    const float* x  = (enc ? D_feats : O_feats) + row * F_LS;
    const float* W1 = enc ? WD1 : WO1;  const float* b1 = enc ? bD1 : bO1;
    const float* W2 = enc ? WD2 : WO2;  const float* b2 = enc ? bD2 : bO2;
    const float* W3 = enc ? WD3 : WO3;  const float* b3 = enc ? bD3 : bO3;

    float a = b1[t];
    #pragma unroll 8
    for (int k = 0; k < F_LS; ++k) a += x[k] * W1[k * NH + t];
    h1[t] = fmaxf(a, 0.f);
    __syncthreads();

    a = b2[t];
    #pragma unroll 8
    for (int k = 0; k < NH; ++k) a += h1[k] * W2[k * NH + t];
    h2[t] = fmaxf(a, 0.f);
    __syncthreads();

    if (t < NO) {
        a = b3[t];
        #pragma unroll 8
        for (int k = 0; k < NH; ++k) a += h2[k] * W3[k * NO + t];
        ev[t] = a;
    }
    __syncthreads();

    const float* Wp = Wp1 + (enc ? NO * PH : 0);
    a = 0.f;
    #pragma unroll 8
    for (int k = 0; k < NO; ++k) a += ev[k] * Wp[k * PH + t];
    if (enc) PBt[t * 128 + row] = a + bp1[t];   // transposed + bias folded
    else     PA[row * PH + t] = a;
}

// ---------------- pair scores (coalesced PBt stream) ----------------
__global__ __launch_bounds__(128) void k_pair(
    const float* __restrict__ PA, const float* __restrict__ PBt,
    const float* __restrict__ Wp2, const float* __restrict__ bp2,
    float* __restrict__ s_pair)
{
    const int i = blockIdx.x;
    const int j = threadIdx.x;
    __shared__ float pa[PH];
    __shared__ float w2s[PH];
    pa[j]  = PA[i * PH + j];
    w2s[j] = Wp2[j];
    __syncthreads();
    float acc = 0.f;
    #pragma unroll 8
    for (int c = 0; c < PH; ++c)
        acc += w2s[c] * fmaxf(pa[c] + PBt[c * 128 + j], 0.f);
    float z = acc + bp2[0];
    float sp = fmaxf(z, 0.f) + log1pf(__expf(-fabsf(z)));
    s_pair[i * 128 + j] = sp;
}

// ------- counting sort by length, DESCENDING, one block, LDS atomics -------
__global__ __launch_bounds__(1024) void k_sort(
    const int* __restrict__ lengths, int* __restrict__ perm)
{
    __shared__ int cnt[130];
    __shared__ int suf[130];
    const int t = threadIdx.x;
    if (t < 130) cnt[t] = 0;
    __syncthreads();
    for (int i = t; i < 16384; i += 1024) atomicAdd(&cnt[lengths[i]], 1);
    __syncthreads();
    if (t < 130) suf[t] = cnt[t];
    __syncthreads();
    for (int d = 1; d < 130; d <<= 1) {
        int v = 0;
        if (t < 130) { v = suf[t]; if (t + d < 130) v += suf[t + d]; }
        __syncthreads();
        if (t < 130) suf[t] = v;
        __syncthreads();
    }
    if (t < 129) cnt[t] = (t + 1 < 130) ? suf[t + 1] : 0;
    __syncthreads();
    for (int i = t; i < 16384; i += 1024) {
        int pos = atomicAdd(&cnt[lengths[i]], 1);
        perm[pos] = i;
    }
}

// ---- GRU: independent 4-wave blocks, identity mapping (CU-load balanced) ---
// grid 1024 x 256 (4 blocks/CU; co-resident ranks {r,r+256,r+512,r+768} sum to
// ~const -> balanced). x staged through LDS double buffer in 8-step phases via
// global_load_lds (lane-linear dest [row][pair l>>2][chunk l&3] = base+l*16B);
// the compiler's vmcnt(0)-before-barrier drain is paid ONCE per 8 steps
// instead of every step. Wave w owns hidden cols [16w,16w+16);
// lane(q=l>>4,n=l&15): pair n, cols 16w+4q+0..3. x-first MFMA ordering.
__global__ __launch_bounds__(256, 4) void k_gru(
    const float* __restrict__ seqs, const int* __restrict__ lengths,
    const int* __restrict__ perm,
    const float* __restrict__ W_ih, const float* __restrict__ b_ih,
    const float* __restrict__ W_hh, const float* __restrict__ b_hh,
    const float* __restrict__ Ws, const float* __restrict__ bs,
    const float* __restrict__ s_pair, float* __restrict__ d_out)
{
    __shared__ __align__(16) f16 hbuf[2][16 * 72];      // [buf][pair][64+8 pad]
    __shared__ __align__(16) float xbuf[2][8][16][16];  // [buf][row][pair][16 f32]
    __shared__ float red[64];
    const int tid = threadIdx.x;
    const int w  = tid >> 6;
    const int l  = tid & 63;
    const int q  = l >> 4;
    const int n  = l & 15;
    const int c  = w * 16 + n;          // W-frag column (m-row of A-tile)
    const int colbase = w * 16 + q * 4; // this lane's 4 hidden cols
    const int pb = blockIdx.x * 16;     // identity mapping
    const float S_RZ = -1.4426950408889634f;   // -log2(e)
    const float S_N  =  2.8853900817779268f;   // 2*log2(e)

    // W fragments (A-operand via m=lane&15):
    f16x8 wh[3][2], wi[3];
    #pragma unroll
    for (int gg = 0; gg < 3; ++gg) {
        const int gb = gg * 64;
        const float s = (gg < 2) ? S_RZ : S_N;
        #pragma unroll
        for (int ks = 0; ks < 2; ++ks)
            #pragma unroll
            for (int j = 0; j < 8; ++j)
                wh[gg][ks][j] = (f16)(W_hh[(ks * 32 + q * 8 + j) * 192 + gb + c] * s);
        #pragma unroll
        for (int j = 0; j < 8; ++j) {
            int k = q * 8 + j;
            wi[gg][j] = (k < FE_N) ? (f16)(W_ih[k * 192 + gb + c] * s) : (f16)0.f;
        }
    }
    // per-reg bias C-vectors and Ws for this lane's 4 cols
    f32x4 c_r, c_z, c_hn, c_xn;
    float wsc[4];
    #pragma unroll
    for (int r = 0; r < 4; ++r) {
        int col = colbase + r;
        c_r[r]  = S_RZ * (b_ih[col] + b_hh[col]);
        c_z[r]  = S_RZ * (b_ih[64 + col] + b_hh[64 + col]);
        c_hn[r] = S_N * b_hh[128 + col];
        c_xn[r] = S_N * b_ih[128 + col];
        wsc[r]  = Ws[col];
    }
    const int myp   = perm[pb + n];      // this lane's pair
    const int mylen = lengths[myp];
    int ml = mylen;
    ml = max(ml, __shfl_xor(ml, 1));
    ml = max(ml, __shfl_xor(ml, 2));
    ml = max(ml, __shfl_xor(ml, 4));
    ml = max(ml, __shfl_xor(ml, 8));
    const int maxlen = __builtin_amdgcn_readfirstlane(ml);

    // staging source: lane covers (pair l>>2, floats [4*(l&3), 4*(l&3)+4))
    const float* xsrc = seqs + (size_t)perm[pb + (l >> 2)] * (T_MAX * FE_N)
                       + (l & 3) * 4;

    // zero h buffer 0 (2304 B = 144 x 16 B)
    if (tid < 144) { f16x8 z8 = {}; *(f16x8*)&hbuf[0][tid * 8] = z8; }

    // stage phase 0 (rows 0..7): wave w loads rows {w, w+4}
    #pragma unroll
    for (int rr = 0; rr < 2; ++rr) {
        const int r8 = w + rr * 4;
        __builtin_amdgcn_global_load_lds(
            (const __attribute__((address_space(1))) void*)(xsrc + (size_t)r8 * FE_N),
            (__attribute__((address_space(3))) void*)&xbuf[0][r8][0][0], 16, 0, 0);
    }
    float hold[4] = {0.f, 0.f, 0.f, 0.f};
    const f16x8 zero8 = {};
    __syncthreads();   // drains phase-0 staging + hbuf zero

    #pragma unroll 1
    for (int t = 0; t < maxlen; ++t) {
        const int cur = t & 1;
        const int xb  = (t >> 3) & 1;
        const int row = t & 7;
        const f16* hb  = hbuf[cur];
        f16*       hbw = hbuf[cur ^ 1];
        // issue LDS reads first (latency), staging + x-convert fill the gap
        f16x8 bh0 = *(const f16x8*)&hb[n * 72 + 8 * q];
        f16x8 bh1 = *(const f16x8*)&hb[n * 72 + 32 + 8 * q];

        // stage NEXT phase once per 8 steps (block-uniform condition)
        if (row == 0 && t + 8 < maxlen) {
            const int nb = xb ^ 1;
            #pragma unroll
            for (int rr = 0; rr < 2; ++rr) {
                const int rl = w + rr * 4;
                int rg = t + 8 + rl;
                rg = rg < T_MAX ? rg : T_MAX - 1;   // rows always allocated
                __builtin_amdgcn_global_load_lds(
                    (const __attribute__((address_space(1))) void*)(xsrc + (size_t)rg * FE_N),
                    (__attribute__((address_space(3))) void*)&xbuf[nb][rl][0][0], 16, 0, 0);
            }
        }

        f16x8 ax = zero8;                 // q>=2 lanes contribute zeros (K pad)
        if (q < 2) {
            const float* xr = &xbuf[xb][row][n][q * 8];
            float4 a0 = *(const float4*)xr;
            float4 a1 = *(const float4*)(xr + 4);
            union { f16x8 v8; hf2 v2[4]; } u;
            u.v2[0] = __builtin_amdgcn_cvt_pkrtz(a0.x, a0.y);
            u.v2[1] = __builtin_amdgcn_cvt_pkrtz(a0.z, a0.w);
            u.v2[2] = __builtin_amdgcn_cvt_pkrtz(a1.x, a1.y);
            u.v2[3] = __builtin_amdgcn_cvt_pkrtz(a1.z, a1.w);
            ax = u.v8;
        }

        // x-first MFMA chains (no LDS dep on first op of r/z/xn)
        f32x4 ar = __builtin_amdgcn_mfma_f32_16x16x32_f16(wi[0], ax, c_r, 0, 0, 0);
        f32x4 az = __builtin_amdgcn_mfma_f32_16x16x32_f16(wi[1], ax, c_z, 0, 0, 0);
        f32x4 xn = __builtin_amdgcn_mfma_f32_16x16x32_f16(wi[2], ax, c_xn, 0, 0, 0);
        ar = __builtin_amdgcn_mfma_f32_16x16x32_f16(wh[0][0], bh0, ar, 0, 0, 0);
        ar = __builtin_amdgcn_mfma_f32_16x16x32_f16(wh[0][1], bh1, ar, 0, 0, 0);
        az = __builtin_amdgcn_mfma_f32_16x16x32_f16(wh[1][0], bh0, az, 0, 0, 0);
        az = __builtin_amdgcn_mfma_f32_16x16x32_f16(wh[1][1], bh1, az, 0, 0, 0);
        f32x4 hn = __builtin_amdgcn_mfma_f32_16x16x32_f16(wh[2][0], bh0, c_hn, 0, 0, 0);
        hn = __builtin_amdgcn_mfma_f32_16x16x32_f16(wh[2][1], bh1, hn, 0, 0, 0);

        const bool live = (t < mylen);
        #pragma unroll
        for (int r = 0; r < 4; ++r) {
            float rg    = __builtin_amdgcn_rcpf(1.f + __builtin_amdgcn_exp2f(ar[r]));
            float zg    = __builtin_amdgcn_rcpf(1.f + __builtin_amdgcn_exp2f(az[r]));
            float inner = fmaf(rg, hn[r], xn[r]);
            float nn    = fmaf(-2.f, __builtin_amdgcn_rcpf(1.f + __builtin_amdgcn_exp2f(inner)), 1.f);
            float hnew  = fmaf(zg, hold[r] - nn, nn);
            hold[r] = live ? hnew : hold[r];
        }
        union { f16x4 v4; hf2 v2[2]; } hu;
        hu.v2[0] = __builtin_amdgcn_cvt_pkrtz(hold[0], hold[1]);
        hu.v2[1] = __builtin_amdgcn_cvt_pkrtz(hold[2], hold[3]);
        *(f16x4*)&hbw[n * 72 + colbase] = hu.v4;
        __syncthreads();
    }

    // epilogue: p_seq = sigmoid(h @ Ws + bs); contrib = s_pair * p_seq
    float part = hold[0] * wsc[0] + hold[1] * wsc[1] +
                 hold[2] * wsc[2] + hold[3] * wsc[3];
    part += __shfl_xor(part, 16);
    part += __shfl_xor(part, 32);          // sum over q: wave-w partial for pair n
    if (l < 16) red[w * 16 + n] = part;
    __syncthreads();
    if (tid < 16) {
        float s = red[tid] + red[16 + tid] + red[32 + tid] + red[48 + tid];
        float pv = fast_sigmoid(s + bs[0]);
        float contrib = s_pair[perm[pb + tid]] * pv;
        #pragma unroll
        for (int off = 1; off < 16; off <<= 1)
            contrib += __shfl_xor(contrib, off);
        if (tid == 0) atomicAdd(d_out, contrib);
    }
}

extern "C" void kernel_launch(void* const* d_in, const int* in_sizes, int n_in,
                              void* d_out, int out_size, void* d_ws, size_t ws_size,
                              hipStream_t stream)
{
    const float* O_feats = (const float*)d_in[0];
    const float* D_feats = (const float*)d_in[1];
    const float* seqs    = (const float*)d_in[2];
    const int*   lengths = (const int*)d_in[3];
    const float* WO1 = (const float*)d_in[4];  const float* bO1 = (const float*)d_in[5];
    const float* WO2 = (const float*)d_in[6];  const float* bO2 = (const float*)d_in[7];
    const float* WO3 = (const float*)d_in[8];  const float* bO3 = (const float*)d_in[9];
    const float* WD1 = (const float*)d_in[10]; const float* bD1 = (const float*)d_in[11];
    const float* WD2 = (const float*)d_in[12]; const float* bD2 = (const float*)d_in[13];
    const float* WD3 = (const float*)d_in[14]; const float* bD3 = (const float*)d_in[15];
    const float* Wp1 = (const float*)d_in[16]; const float* bp1 = (const float*)d_in[17];
    const float* Wp2 = (const float*)d_in[18]; const float* bp2 = (const float*)d_in[19];
    const float* W_ih = (const float*)d_in[20]; const float* b_ih = (const float*)d_in[21];
    const float* W_hh = (const float*)d_in[22]; const float* b_hh = (const float*)d_in[23];
    const float* Ws   = (const float*)d_in[24]; const float* bs   = (const float*)d_in[25];

    float* out    = (float*)d_out;
    float* PA     = (float*)d_ws;              // 16384 f
    float* PBt    = PA + 128 * 128;            // 16384 f (transposed, bp1 folded)
    float* s_pair = PBt + 128 * 128;           // 16384 f
    int*   perm   = (int*)(s_pair + 16384);    // 16384 i

    k_enc<<<256, 128, 0, stream>>>(O_feats, D_feats,
                                   WO1, bO1, WO2, bO2, WO3, bO3,
                                   WD1, bD1, WD2, bD2, WD3, bD3,
                                   Wp1, bp1, PA, PBt, out);
    k_pair<<<128, 128, 0, stream>>>(PA, PBt, Wp2, bp2, s_pair);
    k_sort<<<1, 1024, 0, stream>>>(lengths, perm);
    k_gru<<<1024, 256, 0, stream>>>(seqs, lengths, perm, W_ih, b_ih, W_hh, b_hh,
                                    Ws, bs, s_pair, out);
}

// Round 6
// 327.348 us; speedup vs baseline: 1.1744x; 1.0042x over previous
//
#include <hip/hip_runtime.h>
#include <hip/hip_bf16.h>

#define O_N 128
#define D_N 128
#define F_LS 64
#define T_MAX 128
#define FE_N 16
#define H_GRU 64
#define NH 128
#define NO 64
#define PH 128

typedef _Float16 f16;
typedef __fp16 hf2 __attribute__((ext_vector_type(2)));
typedef f16 f16x4 __attribute__((ext_vector_type(4)));
typedef f16 f16x8 __attribute__((ext_vector_type(8)));
typedef float f32x4 __attribute__((ext_vector_type(4)));

__device__ __forceinline__ float fast_sigmoid(float x) {
    return __builtin_amdgcn_rcpf(1.f + __expf(-x));
}

// ---- fused: encoders (blocks 0..255) + counting sort (block 256) ----------
// enc: PA / transposed-PB (bp1 folded); also zeroes d_out.
// sort: lengths -> perm, descending, 256 threads.
__global__ __launch_bounds__(256) void k_pre(
    const float* __restrict__ O_feats, const float* __restrict__ D_feats,
    const float* __restrict__ WO1, const float* __restrict__ bO1,
    const float* __restrict__ WO2, const float* __restrict__ bO2,
    const float* __restrict__ WO3, const float* __restrict__ bO3,
    const float* __restrict__ WD1, const float* __restrict__ bD1,
    const float* __restrict__ WD2, const float* __restrict__ bD2,
    const float* __restrict__ WD3, const float* __restrict__ bD3,
    const float* __restrict__ Wp1, const float* __restrict__ bp1,
    const int* __restrict__ lengths,
    float* __restrict__ PA, float* __restrict__ PBt,
    int* __restrict__ perm, float* __restrict__ d_out)
{
    const int t = threadIdx.x;
    if (blockIdx.x == 256) {
        // ---------------- counting sort, 256 threads ----------------
        __shared__ int cnt[130];
        __shared__ int suf[130];
        if (t < 130) cnt[t] = 0;
        __syncthreads();
        for (int i = t; i < 16384; i += 256) atomicAdd(&cnt[lengths[i]], 1);
        __syncthreads();
        if (t < 130) suf[t] = cnt[t];
        __syncthreads();
        for (int d = 1; d < 130; d <<= 1) {
            int v = 0;
            if (t < 130) { v = suf[t]; if (t + d < 130) v += suf[t + d]; }
            __syncthreads();
            if (t < 130) suf[t] = v;
            __syncthreads();
        }
        if (t < 129) cnt[t] = (t + 1 < 130) ? suf[t + 1] : 0;
        __syncthreads();
        for (int i = t; i < 16384; i += 256) {
            int pos = atomicAdd(&cnt[lengths[i]], 1);
            perm[pos] = i;
        }
        return;
    }

    // ---------------- encoder, threads 0..127 active ----------------
    __shared__ float h1[NH];
    __shared__ float h2[NH];
    __shared__ float ev[NO];
    const int b = blockIdx.x;
    const int enc = b >> 7;
    const int row = b & 127;
    if (b == 0 && t == 0) d_out[0] = 0.f;

    const float* x  = (enc ? D_feats : O_feats) + row * F_LS;
    const float* W1 = enc ? WD1 : WO1;  const float* b1 = enc ? bD1 : bO1;
    const float* W2 = enc ? WD2 : WO2;  const float* b2 = enc ? bD2 : bO2;
    const float* W3 = enc ? WD3 : WO3;  const float* b3 = enc ? bD3 : bO3;

    if (t < 128) {
        float a = b1[t];
        #pragma unroll 8
        for (int k = 0; k < F_LS; ++k) a += x[k] * W1[k * NH + t];
        h1[t] = fmaxf(a, 0.f);
    }
    __syncthreads();

    if (t < 128) {
        float a = b2[t];
        #pragma unroll 8
        for (int k = 0; k < NH; ++k) a += h1[k] * W2[k * NH + t];
        h2[t] = fmaxf(a, 0.f);
    }
    __syncthreads();

    if (t < NO) {
        float a = b3[t];
        #pragma unroll 8
        for (int k = 0; k < NH; ++k) a += h2[k] * W3[k * NO + t];
        ev[t] = a;
    }
    __syncthreads();

    if (t < 128) {
        const float* Wp = Wp1 + (enc ? NO * PH : 0);
        float a = 0.f;
        #pragma unroll 8
        for (int k = 0; k < NO; ++k) a += ev[k] * Wp[k * PH + t];
        if (enc) PBt[t * 128 + row] = a + bp1[t];   // transposed + bias folded
        else     PA[row * PH + t] = a;
    }
}

// ---- GRU: independent 4-wave blocks, identity mapping (CU-load balanced) ---
// grid 1024 x 256 (4 blocks/CU; co-resident ranks {r,r+256,r+512,r+768} sum to
// ~const -> balanced). x staged through LDS double buffer in 8-step phases via
// global_load_lds; RAW barriers with counted waits: lgkmcnt(0)+s_barrier per
// step, vmcnt(0) only at row 7 (staging issued at row srow=blk&3 -> 4-7 steps
// of latency hiding, per-block stagger de-convoys CUs). xbuf transposed
// [row][chunk][pair] (src-side remap, LDS dest lane-linear): 8-way -> 4-way
// bank conflict. Wave w owns hidden cols [16w,16w+16); lane(q,n): pair n,
// cols 16w+4q+0..3. x-first MFMA ordering. Pair-score MLP fused in epilogue.
__global__ __launch_bounds__(256, 4) void k_gru(
    const float* __restrict__ seqs, const int* __restrict__ lengths,
    const int* __restrict__ perm,
    const float* __restrict__ W_ih, const float* __restrict__ b_ih,
    const float* __restrict__ W_hh, const float* __restrict__ b_hh,
    const float* __restrict__ Ws, const float* __restrict__ bs,
    const float* __restrict__ PA, const float* __restrict__ PBt,
    const float* __restrict__ Wp2, const float* __restrict__ bp2,
    float* __restrict__ d_out)
{
    __shared__ __align__(16) f16 hbuf[2][16 * 72];      // [buf][pair][64+8 pad]
    __shared__ __align__(16) float4 xbuf[2][8][64];     // [buf][row][chunk*16+pair]
    __shared__ float red[64];
    const int tid = threadIdx.x;
    const int w  = tid >> 6;
    const int l  = tid & 63;
    const int q  = l >> 4;
    const int n  = l & 15;
    const int c  = w * 16 + n;          // W-frag column (m-row of A-tile)
    const int colbase = w * 16 + q * 4; // this lane's 4 hidden cols
    const int pb = blockIdx.x * 16;     // identity mapping
    const int srow = blockIdx.x & 3;    // staging-phase stagger
    const float S_RZ = -1.4426950408889634f;   // -log2(e)
    const float S_N  =  2.8853900817779268f;   // 2*log2(e)

    // W fragments (A-operand via m=lane&15):
    f16x8 wh[3][2], wi[3];
    #pragma unroll
    for (int gg = 0; gg < 3; ++gg) {
        const int gb = gg * 64;
        const float s = (gg < 2) ? S_RZ : S_N;
        #pragma unroll
        for (int ks = 0; ks < 2; ++ks)
            #pragma unroll
            for (int j = 0; j < 8; ++j)
                wh[gg][ks][j] = (f16)(W_hh[(ks * 32 + q * 8 + j) * 192 + gb + c] * s);
        #pragma unroll
        for (int j = 0; j < 8; ++j) {
            int k = q * 8 + j;
            wi[gg][j] = (k < FE_N) ? (f16)(W_ih[k * 192 + gb + c] * s) : (f16)0.f;
        }
    }
    // per-reg bias C-vectors and Ws for this lane's 4 cols
    f32x4 c_r, c_z, c_hn, c_xn;
    float wsc[4];
    #pragma unroll
    for (int r = 0; r < 4; ++r) {
        int col = colbase + r;
        c_r[r]  = S_RZ * (b_ih[col] + b_hh[col]);
        c_z[r]  = S_RZ * (b_ih[64 + col] + b_hh[64 + col]);
        c_hn[r] = S_N * b_hh[128 + col];
        c_xn[r] = S_N * b_ih[128 + col];
        wsc[r]  = Ws[col];
    }
    const int myp   = perm[pb + n];      // this lane's pair
    const int mylen = lengths[myp];
    int ml = mylen;
    ml = max(ml, __shfl_xor(ml, 1));
    ml = max(ml, __shfl_xor(ml, 2));
    ml = max(ml, __shfl_xor(ml, 4));
    ml = max(ml, __shfl_xor(ml, 8));
    const int maxlen = __builtin_amdgcn_readfirstlane(ml);

    // staging source: lane l covers slot l = (chunk l>>4, pair l&15)
    const float* xsrc = seqs + (size_t)perm[pb + (l & 15)] * (T_MAX * FE_N)
                       + (l >> 4) * 4;

    // zero h buffer 0 (2304 B = 144 x 16 B)
    if (tid < 144) { f16x8 z8 = {}; *(f16x8*)&hbuf[0][tid * 8] = z8; }

    // stage phase 0 (rows 0..7): wave w loads rows {w, w+4}
    #pragma unroll
    for (int rr = 0; rr < 2; ++rr) {
        const int r8 = w + rr * 4;
        __builtin_amdgcn_global_load_lds(
            (const __attribute__((address_space(1))) void*)(xsrc + (size_t)r8 * FE_N),
            (__attribute__((address_space(3))) void*)&xbuf[0][r8][0], 16, 0, 0);
    }
    float hold[4] = {0.f, 0.f, 0.f, 0.f};
    const f16x8 zero8 = {};
    __syncthreads();   // full drain: phase-0 staging + hbuf zero

    #pragma unroll 1
    for (int t = 0; t < maxlen; ++t) {
        const int cur = t & 1;
        const int xb  = (t >> 3) & 1;
        const int row = t & 7;
        const f16* hb  = hbuf[cur];
        f16*       hbw = hbuf[cur ^ 1];
        // issue LDS reads first (latency), staging + x-convert fill the gap
        f16x8 bh0 = *(const f16x8*)&hb[n * 72 + 8 * q];
        f16x8 bh1 = *(const f16x8*)&hb[n * 72 + 32 + 8 * q];

        // stage NEXT phase once per 8 steps at per-block stagger row
        if (row == srow && (t - srow) + 8 < maxlen) {
            const int nb = xb ^ 1;
            const int tp8 = (t - srow) + 8;
            #pragma unroll
            for (int rr = 0; rr < 2; ++rr) {
                const int rl = w + rr * 4;
                int rg = tp8 + rl;
                rg = rg < T_MAX ? rg : T_MAX - 1;   // rows always allocated
                __builtin_amdgcn_global_load_lds(
                    (const __attribute__((address_space(1))) void*)(xsrc + (size_t)rg * FE_N),
                    (__attribute__((address_space(3))) void*)&xbuf[nb][rl][0], 16, 0, 0);
            }
        }

        f16x8 ax = zero8;                 // q>=2 lanes contribute zeros (K pad)
        if (q < 2) {
            float4 a0 = xbuf[xb][row][32 * q + n];        // chunk 2q
            float4 a1 = xbuf[xb][row][32 * q + 16 + n];   // chunk 2q+1
            union { f16x8 v8; hf2 v2[4]; } u;
            u.v2[0] = __builtin_amdgcn_cvt_pkrtz(a0.x, a0.y);
            u.v2[1] = __builtin_amdgcn_cvt_pkrtz(a0.z, a0.w);
            u.v2[2] = __builtin_amdgcn_cvt_pkrtz(a1.x, a1.y);
            u.v2[3] = __builtin_amdgcn_cvt_pkrtz(a1.z, a1.w);
            ax = u.v8;
        }

        // x-first MFMA chains (no LDS dep on first op of r/z/xn)
        f32x4 ar = __builtin_amdgcn_mfma_f32_16x16x32_f16(wi[0], ax, c_r, 0, 0, 0);
        f32x4 az = __builtin_amdgcn_mfma_f32_16x16x32_f16(wi[1], ax, c_z, 0, 0, 0);
        f32x4 xn = __builtin_amdgcn_mfma_f32_16x16x32_f16(wi[2], ax, c_xn, 0, 0, 0);
        ar = __builtin_amdgcn_mfma_f32_16x16x32_f16(wh[0][0], bh0, ar, 0, 0, 0);
        ar = __builtin_amdgcn_mfma_f32_16x16x32_f16(wh[0][1], bh1, ar, 0, 0, 0);
        az = __builtin_amdgcn_mfma_f32_16x16x32_f16(wh[1][0], bh0, az, 0, 0, 0);
        az = __builtin_amdgcn_mfma_f32_16x16x32_f16(wh[1][1], bh1, az, 0, 0, 0);
        f32x4 hn = __builtin_amdgcn_mfma_f32_16x16x32_f16(wh[2][0], bh0, c_hn, 0, 0, 0);
        hn = __builtin_amdgcn_mfma_f32_16x16x32_f16(wh[2][1], bh1, hn, 0, 0, 0);

        const bool live = (t < mylen);
        #pragma unroll
        for (int r = 0; r < 4; ++r) {
            float rg    = __builtin_amdgcn_rcpf(1.f + __builtin_amdgcn_exp2f(ar[r]));
            float zg    = __builtin_amdgcn_rcpf(1.f + __builtin_amdgcn_exp2f(az[r]));
            float inner = fmaf(rg, hn[r], xn[r]);
            float nn    = fmaf(-2.f, __builtin_amdgcn_rcpf(1.f + __builtin_amdgcn_exp2f(inner)), 1.f);
            float hnew  = fmaf(zg, hold[r] - nn, nn);
            hold[r] = live ? hnew : hold[r];
        }
        union { f16x4 v4; hf2 v2[2]; } hu;
        hu.v2[0] = __builtin_amdgcn_cvt_pkrtz(hold[0], hold[1]);
        hu.v2[1] = __builtin_amdgcn_cvt_pkrtz(hold[2], hold[3]);
        *(f16x4*)&hbw[n * 72 + colbase] = hu.v4;

        // counted-wait barrier: drain vmem only at row 7 (staging has 4-7
        // steps of lead); every step drains LDS (h write) then s_barrier.
        if (row == 7) asm volatile("s_waitcnt vmcnt(0)" ::: "memory");
        asm volatile("s_waitcnt lgkmcnt(0)" ::: "memory");
        __builtin_amdgcn_s_barrier();
    }

    // ---- epilogue: p_seq = sigmoid(h @ Ws + bs); fused pair-score MLP ----
    float part = hold[0] * wsc[0] + hold[1] * wsc[1] +
                 hold[2] * wsc[2] + hold[3] * wsc[3];
    part += __shfl_xor(part, 16);
    part += __shfl_xor(part, 32);          // sum over q: wave-w partial for pair n
    if (l < 16) red[w * 16 + n] = part;
    __syncthreads();

    // 16 threads per pair: s_pair = softplus(Wp2 . relu(PA_i + PBt_j))
    const int pp = tid >> 4;               // pair 0..15
    const int u  = tid & 15;
    const int pidx = perm[pb + pp];
    const int ii = pidx >> 7;
    const int jj = pidx & 127;
    float acc = 0.f;
    #pragma unroll
    for (int cc = u; cc < PH; cc += 16)
        acc += Wp2[cc] * fmaxf(PA[ii * PH + cc] + PBt[cc * 128 + jj], 0.f);
    acc += __shfl_xor(acc, 1);
    acc += __shfl_xor(acc, 2);
    acc += __shfl_xor(acc, 4);
    acc += __shfl_xor(acc, 8);
    float contrib = 0.f;
    if (u == 0) {
        float z  = acc + bp2[0];
        float sp = fmaxf(z, 0.f) + log1pf(__expf(-fabsf(z)));
        float s  = red[pp] + red[16 + pp] + red[32 + pp] + red[48 + pp];
        float pv = fast_sigmoid(s + bs[0]);
        contrib  = sp * pv;
    }
    __syncthreads();
    if (u == 0) red[pp] = contrib;
    __syncthreads();
    if (tid == 0) {
        float tot = 0.f;
        #pragma unroll
        for (int k = 0; k < 16; ++k) tot += red[k];
        atomicAdd(d_out, tot);
    }
}

extern "C" void kernel_launch(void* const* d_in, const int* in_sizes, int n_in,
                              void* d_out, int out_size, void* d_ws, size_t ws_size,
                              hipStream_t stream)
{
    const float* O_feats = (const float*)d_in[0];
    const float* D_feats = (const float*)d_in[1];
    const float* seqs    = (const float*)d_in[2];
    const int*   lengths = (const int*)d_in[3];
    const float* WO1 = (const float*)d_in[4];  const float* bO1 = (const float*)d_in[5];
    const float* WO2 = (const float*)d_in[6];  const float* bO2 = (const float*)d_in[7];
    const float* WO3 = (const float*)d_in[8];  const float* bO3 = (const float*)d_in[9];
    const float* WD1 = (const float*)d_in[10]; const float* bD1 = (const float*)d_in[11];
    const float* WD2 = (const float*)d_in[12]; const float* bD2 = (const float*)d_in[13];
    const float* WD3 = (const float*)d_in[14]; const float* bD3 = (const float*)d_in[15];
    const float* Wp1 = (const float*)d_in[16]; const float* bp1 = (const float*)d_in[17];
    const float* Wp2 = (const float*)d_in[18]; const float* bp2 = (const float*)d_in[19];
    const float* W_ih = (const float*)d_in[20]; const float* b_ih = (const float*)d_in[21];
    const float* W_hh = (const float*)d_in[22]; const float* b_hh = (const float*)d_in[23];
    const float* Ws   = (const float*)d_in[24]; const float* bs   = (const float*)d_in[25];

    float* out    = (float*)d_out;
    float* PA     = (float*)d_ws;              // 16384 f
    float* PBt    = PA + 128 * 128;            // 16384 f (transposed, bp1 folded)
    int*   perm   = (int*)(PBt + 128 * 128);   // 16384 i

    k_pre<<<257, 256, 0, stream>>>(O_feats, D_feats,
                                   WO1, bO1, WO2, bO2, WO3, bO3,
                                   WD1, bD1, WD2, bD2, WD3, bD3,
                                   Wp1, bp1, lengths, PA, PBt, perm, out);
    k_gru<<<1024, 256, 0, stream>>>(seqs, lengths, perm, W_ih, b_ih, W_hh, b_hh,
                                    Ws, bs, PA, PBt, Wp2, bp2, out);
}